// Round 2
// baseline (129.353 us; speedup 1.0000x reference)
//
#include <hip/hip_runtime.h>
#include <math.h>

typedef __attribute__((ext_vector_type(8))) short short8;
typedef __attribute__((ext_vector_type(16))) float f32x16;
typedef __attribute__((ext_vector_type(2))) unsigned uintx2;

#define XS_STRIDE 72   // shorts per (row,col) cell: 64 ci + 8 pad -> 144 B, 16B-aligned
#define RING 6         // LDS row ring: 4 live rows + 2 incoming

__device__ __forceinline__ short f2bf(float f) {
    union { float f; unsigned u; } v; v.f = f;
    unsigned r = (v.u + 0x7FFFu + ((v.u >> 16) & 1u)) >> 16;
    return (short)r;
}

// packed f32x2 -> bf16x2 (RNE on gfx950)
__device__ __forceinline__ unsigned cvt_pk_bf16(float lo, float hi) {
    unsigned r;
    asm("v_cvt_pk_bf16_f32 %0, %1, %2" : "=v"(r) : "v"(lo), "v"(hi));
    return r;
}

// Non-draining barrier (T4): drains LDS ops only; global loads stay in
// flight across the barrier (__syncthreads would emit s_waitcnt vmcnt(0)).
__device__ __forceinline__ void bar_nodrain() {
    __builtin_amdgcn_sched_barrier(0);
    asm volatile("s_waitcnt lgkmcnt(0)" ::: "memory");
    __builtin_amdgcn_s_barrier();
    __builtin_amdgcn_sched_barrier(0);
}

// Build weight A-fragments: wfrag[p][q][lane][j], p=ph*2+pw, q=tap*4+ci_block.
__global__ void prep(const float* __restrict__ w, short* __restrict__ wfrag) {
    int idx = blockIdx.x * 256 + threadIdx.x;   // 0 .. 32767
    int j    = idx & 7;
    int lane = (idx >> 3) & 63;
    int q    = (idx >> 9) & 15;
    int p    = idx >> 13;
    int co = lane & 31, hf = lane >> 5;
    int ci = (q & 3) * 16 + hf * 8 + j;
    int tq = q >> 2, a = tq >> 1, b = tq & 1;
    int ph = p >> 1, pw = p & 1;
    int kh = 2 * a + 1 - ph, kw = 2 * b + 1 - pw;
    wfrag[idx] = f2bf(w[((ci * 32 + co) * 4 + kh) * 4 + kw]);
}

// Block = (n, col quarter jq [32 cols], row strip st [4 input-row pairs]).
// 6-row LDS ring, 4 pipelined steps with T14 issue-early/write-late staging;
// non-draining barriers keep the staged loads in flight a full step.
// Per step each wave runs both row-pairs interleaved (shared middle row):
// 24 ds_read_b128 feed 32 MFMAs. Output: non-atomic per-strip partials.
__global__ __launch_bounds__(256, 3) void convt_mfma(
    const float* __restrict__ x, const short* __restrict__ wfrag,
    const float* __restrict__ conv_b, float* __restrict__ partials)
{
    __shared__ short xs[RING][34][XS_STRIDE];   // 29,376 B
    __shared__ float minbuf[2][2][4][32];       // [step parity][rp][wave][col], 2 KB

    // XCD-aware bijective swizzle (1024 % 8 == 0): neighbors share an L2.
    int blk = ((blockIdx.x & 7) << 7) | (blockIdx.x >> 3);
    const int jq = blk & 3;                 // column quarter
    const int st = (blk >> 2) & 15;         // row strip (8 input rows)
    const int n  = blk >> 6;
    const int t  = threadIdx.x;
    const int i0 = st * 8;                  // first input row of strip

    const int wv = t >> 6, lane = t & 63;   // wave = output parity (ph,pw)
    const int ph = wv >> 1, pw = wv & 1;
    const int ln = lane & 31, half = lane >> 5;

    // ---- A fragments + conv-bias seed (C/D row = (reg&3)+8*(reg>>2)+4*half) ----
    short8 af[16];
    {
        const short8* wf = (const short8*)(wfrag + wv * 8192);
        #pragma unroll
        for (int q = 0; q < 16; ++q) af[q] = wf[q * 64 + lane];
    }
    float cb[16];
    #pragma unroll
    for (int reg = 0; reg < 16; ++reg)
        cb[reg] = conv_b[(reg & 3) + 8 * (reg >> 2) + 4 * half];

    const float* xn = x + (size_t)n * 64 * 128 * 128;

    // staging maps: main: col=t&31, 8 consecutive ci=(t>>5)*8 per row
    const int col  = t & 31;
    const int cib  = (t >> 5) * 8;
    const int gcol = jq * 32 + col;
    // halo (per step): 2 rows x 2 sides x 64 ci -> 1 value/thread
    const int hrow = t >> 7, hside = (t >> 6) & 1, hci = t & 63;
    const int hgc  = jq * 32 + (hside ? 32 : -1);
    const int sl_base = i0 % RING;          // ring slot of row (i0-1)

    // ---- prologue: stage rows i0-1 .. i0+2 directly ----
    #pragma unroll
    for (int r = 0; r < 4; ++r) {
        int gi = i0 - 1 + r;
        int slot = sl_base + r; if (slot >= RING) slot -= RING;
        bool rowok = (unsigned)gi < 128u;
        int gic = rowok ? gi : 0;
        const float* px = xn + ((size_t)cib * 128 + gic) * 128 + gcol;
        float v[8];
        #pragma unroll
        for (int c = 0; c < 8; ++c) v[c] = rowok ? px[c * 16384] : 0.f;
        uintx2 u0, u1;
        u0.x = cvt_pk_bf16(v[0], v[1]); u0.y = cvt_pk_bf16(v[2], v[3]);
        u1.x = cvt_pk_bf16(v[4], v[5]); u1.y = cvt_pk_bf16(v[6], v[7]);
        *(uintx2*)&xs[slot][col + 1][cib]     = u0;
        *(uintx2*)&xs[slot][col + 1][cib + 4] = u1;
    }
    {   // prologue halo: r=t>>6 (4 rows), ci=t&63, both sides
        int r = t >> 6, ci = t & 63, gi = i0 - 1 + r;
        int slot = sl_base + r; if (slot >= RING) slot -= RING;
        #pragma unroll
        for (int side = 0; side < 2; ++side) {
            int gc = jq * 32 + (side ? 32 : -1);
            float v = ((unsigned)gi < 128u && (unsigned)gc < 128u)
                    ? xn[((size_t)ci * 128 + gi) * 128 + gc] : 0.f;
            xs[slot][side ? 33 : 0][ci] = f2bf(v);
        }
    }

    // ---- prefetch regs + issue helper (issue early, write after compute) ----
    float pf[2][8]; float pfh;
    auto issue = [&](int r0) {
        #pragma unroll
        for (int r2 = 0; r2 < 2; ++r2) {
            int gi = r0 + r2;
            bool rowok = (unsigned)gi < 128u;
            int gic = rowok ? gi : 0;
            const float* px = xn + ((size_t)cib * 128 + gic) * 128 + gcol;
            #pragma unroll
            for (int c = 0; c < 8; ++c) pf[r2][c] = rowok ? px[c * 16384] : 0.f;
        }
        int gi = r0 + hrow;
        pfh = ((unsigned)gi < 128u && (unsigned)hgc < 128u)
            ? xn[((size_t)hci * 128 + gi) * 128 + hgc] : 0.f;
    };
    issue(i0 + 3);          // rows i0+3, i0+4 fly through the barrier + step 0

    bar_nodrain();

    float osum = 0.f;
    const int rpr = t >> 6;            // reduce map (valid for t<128)
    const int pw2 = (t >> 5) & 1;
    const int jl  = t & 31;

    int rbase = sl_base;               // slot offset of row (i0+2k-1)
    #pragma unroll
    for (int k = 0; k < 4; ++k) {
        const int kb = k & 1;
        // rows: rp0 uses ridx {ph, 1+ph}, rp1 uses {1+ph, 2+ph}; 1+ph shared
        int s0 = rbase + ph; if (s0 >= RING) s0 -= RING;
        int s1 = s0 + 1;     if (s1 >= RING) s1 -= RING;
        int s2 = s1 + 1;     if (s2 >= RING) s2 -= RING;

        f32x16 acc0, acc1;
        #pragma unroll
        for (int reg = 0; reg < 16; ++reg) { acc0[reg] = cb[reg]; acc1[reg] = cb[reg]; }
        __builtin_amdgcn_s_setprio(1);
        #pragma unroll
        for (int b = 0; b < 2; ++b) {
            int colp = ln + (pw - b) + 1;
            const short* p0 = &xs[s0][colp][half * 8];
            const short* p1 = &xs[s1][colp][half * 8];
            const short* p2 = &xs[s2][colp][half * 8];
            #pragma unroll
            for (int c = 0; c < 4; ++c) {
                short8 Fs = *(const short8*)(p1 + c * 16);   // shared fragment
                acc0 = __builtin_amdgcn_mfma_f32_32x32x16_bf16(af[4*b+c],   Fs, acc0, 0, 0, 0);
                acc1 = __builtin_amdgcn_mfma_f32_32x32x16_bf16(af[8+4*b+c], Fs, acc1, 0, 0, 0);
                short8 F0 = *(const short8*)(p0 + c * 16);
                acc0 = __builtin_amdgcn_mfma_f32_32x32x16_bf16(af[8+4*b+c], F0, acc0, 0, 0, 0);
                short8 F2 = *(const short8*)(p2 + c * 16);
                acc1 = __builtin_amdgcn_mfma_f32_32x32x16_bf16(af[4*b+c],   F2, acc1, 0, 0, 0);
            }
        }
        __builtin_amdgcn_s_setprio(0);

        // tree min-reduce (depth ~5 instead of 15-deep serial chain)
        float mn0, mn1;
        {
            float a = fminf(fminf(acc0[0], acc0[1]), fminf(acc0[2], acc0[3]));
            float b2 = fminf(fminf(acc0[4], acc0[5]), fminf(acc0[6], acc0[7]));
            float c = fminf(fminf(acc0[8], acc0[9]), fminf(acc0[10], acc0[11]));
            float d = fminf(fminf(acc0[12], acc0[13]), fminf(acc0[14], acc0[15]));
            mn0 = fminf(fminf(a, b2), fminf(c, d));
            a = fminf(fminf(acc1[0], acc1[1]), fminf(acc1[2], acc1[3]));
            b2 = fminf(fminf(acc1[4], acc1[5]), fminf(acc1[6], acc1[7]));
            c = fminf(fminf(acc1[8], acc1[9]), fminf(acc1[10], acc1[11]));
            d = fminf(fminf(acc1[12], acc1[13]), fminf(acc1[14], acc1[15]));
            mn1 = fminf(fminf(a, b2), fminf(c, d));
        }
        mn0 = fminf(mn0, __shfl_xor(mn0, 32, 64));
        mn1 = fminf(mn1, __shfl_xor(mn1, 32, 64));
        if (half == 0) {
            minbuf[kb][0][wv][ln] = mn0;
            minbuf[kb][1][wv][ln] = mn1;
        }

        // write prefetched rows i0+2k+3, i0+2k+4 into slots rbase+4, rbase+5
        // (disjoint from slots rbase..rbase+3 any wave reads this step),
        // then issue the next pair's loads (they stay in flight through the
        // non-draining barrier, consumed one full step later).
        if (k < 3) {
            int ws0 = rbase + 4; if (ws0 >= RING) ws0 -= RING;
            int ws1 = ws0 + 1;   if (ws1 >= RING) ws1 -= RING;
            #pragma unroll
            for (int r2 = 0; r2 < 2; ++r2) {
                int slot = r2 ? ws1 : ws0;
                uintx2 u0, u1;
                u0.x = cvt_pk_bf16(pf[r2][0], pf[r2][1]);
                u0.y = cvt_pk_bf16(pf[r2][2], pf[r2][3]);
                u1.x = cvt_pk_bf16(pf[r2][4], pf[r2][5]);
                u1.y = cvt_pk_bf16(pf[r2][6], pf[r2][7]);
                *(uintx2*)&xs[slot][col + 1][cib]     = u0;
                *(uintx2*)&xs[slot][col + 1][cib + 4] = u1;
            }
            xs[hrow ? ws1 : ws0][hside ? 33 : 0][hci] = f2bf(pfh);
            if (k < 2) issue(i0 + 2 * k + 5);
        }
        bar_nodrain();
        if (t < 128)    // ph-pair sum, accumulated in register across steps
            osum += minbuf[kb][rpr][pw2][jl] + minbuf[kb][rpr][2 + pw2][jl];
        rbase += 2; if (rbase >= RING) rbase -= RING;
    }

    // rp0+rp1 combine -> one non-atomic partial store per output column
    float* sbuf = &minbuf[0][0][0][0];   // disjoint from last-read minbuf[1]
    if (t < 128) sbuf[t] = osum;
    bar_nodrain();
    if (t < 64) {
        float v = sbuf[t] + sbuf[t + 64];
        int ow = ((jq * 32 + (t & 31)) << 1) | ((t >> 5) & 1);
        partials[(size_t)st * 4096 + n * 256 + ow] = v;
    }
}

// Sum 16 strip-partials, GELU(tanh) + bias.
__global__ void finalize(const float* __restrict__ partials,
                         const float* __restrict__ bias, float* __restrict__ out)
{
    int idx = blockIdx.x * 256 + threadIdx.x;  // 0..4095
    float s = 0.f;
    #pragma unroll
    for (int st = 0; st < 16; ++st) s += partials[st * 4096 + idx];
    float u = 0.7978845608028654f * (s + 0.044715f * s * s * s);
    out[idx] = 0.5f * s * (1.f + tanhf(u)) + bias[0];
}

extern "C" void kernel_launch(void* const* d_in, const int* in_sizes, int n_in,
                              void* d_out, int out_size, void* d_ws, size_t ws_size,
                              hipStream_t stream) {
    const float* x      = (const float*)d_in[0];   // [16,64,128,128]
    const float* w      = (const float*)d_in[1];   // [64,32,4,4]
    const float* conv_b = (const float*)d_in[2];   // [32]
    const float* bias   = (const float*)d_in[3];   // [1]
    float* out = (float*)d_out;                    // 16*256

    short* wfrag    = (short*)d_ws;                      // 64 KB
    float* partials = (float*)((char*)d_ws + 65536);     // 16*4096 floats = 256 KB

    hipLaunchKernelGGL(prep, dim3(128), dim3(256), 0, stream, w, wfrag);
    hipLaunchKernelGGL(convt_mfma, dim3(16 * 16 * 4), dim3(256), 0, stream,
                       x, wfrag, conv_b, partials);
    hipLaunchKernelGGL(finalize, dim3(16), dim3(256), 0, stream,
                       partials, bias, out);
}

// Round 3
// 115.767 us; speedup vs baseline: 1.1174x; 1.1174x over previous
//
#include <hip/hip_runtime.h>
#include <math.h>

typedef __attribute__((ext_vector_type(8))) short short8;
typedef __attribute__((ext_vector_type(16))) float f32x16;
typedef __attribute__((ext_vector_type(2))) unsigned uintx2;

#define XS_STRIDE 72   // shorts per (row,col) cell: 64 ci + 8 pad -> 144 B, 16B-aligned
#define NROWS 10       // rows staged per strip: i0-1 .. i0+8 (all resident, no ring)

__device__ __forceinline__ short f2bf(float f) {
    union { float f; unsigned u; } v; v.f = f;
    unsigned r = (v.u + 0x7FFFu + ((v.u >> 16) & 1u)) >> 16;
    return (short)r;
}

// packed f32x2 -> bf16x2 (RNE on gfx950)
__device__ __forceinline__ unsigned cvt_pk_bf16(float lo, float hi) {
    unsigned r;
    asm("v_cvt_pk_bf16_f32 %0, %1, %2" : "=v"(r) : "v"(lo), "v"(hi));
    return r;
}

// Barrier that drains LDS ops only (no vmcnt(0) like __syncthreads).
__device__ __forceinline__ void bar_lds() {
    asm volatile("s_waitcnt lgkmcnt(0)" ::: "memory");
    __builtin_amdgcn_s_barrier();
}

// Build weight A-fragments: wfrag[p][q][lane][j], p=ph*2+pw, q=tap*4+ci_block.
__global__ void prep(const float* __restrict__ w, short* __restrict__ wfrag) {
    int idx = blockIdx.x * 256 + threadIdx.x;   // 0 .. 32767
    int j    = idx & 7;
    int lane = (idx >> 3) & 63;
    int q    = (idx >> 9) & 15;
    int p    = idx >> 13;
    int co = lane & 31, hf = lane >> 5;
    int ci = (q & 3) * 16 + hf * 8 + j;
    int tq = q >> 2, a = tq >> 1, b = tq & 1;
    int ph = p >> 1, pw = p & 1;
    int kh = 2 * a + 1 - ph, kw = 2 * b + 1 - pw;
    wfrag[idx] = f2bf(w[((ci * 32 + co) * 4 + kh) * 4 + kw]);
}

// Block = (n, col quarter jq [32 cols], row strip st [8 input rows]).
// Whole strip (10 rows incl. halo) staged once -> ONE barrier -> 4 compute
// steps run wave-local with NO barriers and NO LDS writes (min over co is
// within-wave; height-sum is linear -> register accumulate) -> ONE barrier
// -> 4-parity combine. Waves drift freely for latency hiding.
__global__ __launch_bounds__(256, 3) void convt_mfma(
    const float* __restrict__ x, const short* __restrict__ wfrag,
    const float* __restrict__ conv_b, float* __restrict__ partials)
{
    __shared__ short xs[NROWS][34][XS_STRIDE];   // 48,960 B
    __shared__ float minbuf[4][32];              // [wave][col]

    // XCD-aware bijective swizzle (1024 % 8 == 0)
    int blk = ((blockIdx.x & 7) << 7) | (blockIdx.x >> 3);
    const int jq = blk & 3;                 // column quarter
    const int st = (blk >> 2) & 15;         // row strip
    const int n  = blk >> 6;
    const int t  = threadIdx.x;
    const int i0 = st * 8;                  // first input row of strip

    const int wv = t >> 6, lane = t & 63;   // wave = output parity (ph,pw)
    const int ph = wv >> 1, pw = wv & 1;
    const int ln = lane & 31, half = lane >> 5;

    // ---- A fragments + conv-bias seed (C/D row = (reg&3)+8*(reg>>2)+4*half) ----
    short8 af[16];
    {
        const short8* wf = (const short8*)(wfrag + wv * 8192);
        #pragma unroll
        for (int q = 0; q < 16; ++q) af[q] = wf[q * 64 + lane];
    }
    float cb[16];
    #pragma unroll
    for (int reg = 0; reg < 16; ++reg)
        cb[reg] = conv_b[(reg & 3) + 8 * (reg >> 2) + 4 * half];

    const float* xn = x + (size_t)n * 64 * 128 * 128;

    // staging map: col=t&31, 8 consecutive ci=(t>>5)*8 per row
    const int col  = t & 31;
    const int cib  = (t >> 5) * 8;
    const int gcol = jq * 32 + col;

    // ---- halo loads issued first: 10 rows x 2 sides x 64 ci = 5 per thread ----
    float hv[5];
    #pragma unroll
    for (int q = 0; q < 5; ++q) {
        int idx = q * 256 + t;
        int r = idx >> 7, side = (idx >> 6) & 1, ci = idx & 63;
        int gi = i0 - 1 + r;
        int gc = jq * 32 + (side ? 32 : -1);
        hv[q] = ((unsigned)gi < 128u && (unsigned)gc < 128u)
              ? xn[((size_t)ci * 128 + gi) * 128 + gc] : 0.f;
    }

    // ---- core rows: depth-2 software pipeline (8-16 loads in flight) ----
    float pfA[8], pfB[8];
    auto load_row = [&](int r, float* dst) {
        int gi = i0 - 1 + r;
        bool rowok = (unsigned)gi < 128u;
        int gic = rowok ? gi : 0;
        const float* px = xn + ((size_t)cib * 128 + gic) * 128 + gcol;
        #pragma unroll
        for (int c = 0; c < 8; ++c) dst[c] = rowok ? px[c * 16384] : 0.f;
    };
    auto write_row = [&](int r, const float* src) {
        uintx2 u0, u1;
        u0.x = cvt_pk_bf16(src[0], src[1]); u0.y = cvt_pk_bf16(src[2], src[3]);
        u1.x = cvt_pk_bf16(src[4], src[5]); u1.y = cvt_pk_bf16(src[6], src[7]);
        *(uintx2*)&xs[r][col + 1][cib]     = u0;
        *(uintx2*)&xs[r][col + 1][cib + 4] = u1;
    };
    load_row(0, pfA);
    load_row(1, pfB);
    #pragma unroll
    for (int r = 0; r < NROWS; r += 2) {
        write_row(r, pfA);
        if (r + 2 < NROWS) load_row(r + 2, pfA);
        write_row(r + 1, pfB);
        if (r + 3 < NROWS) load_row(r + 3, pfB);
    }
    // halo writes (b16 scalar)
    #pragma unroll
    for (int q = 0; q < 5; ++q) {
        int idx = q * 256 + t;
        int r = idx >> 7, side = (idx >> 6) & 1, ci = idx & 63;
        xs[r][side ? 33 : 0][ci] = f2bf(hv[q]);
    }

    bar_lds();

    // ---- 4 compute steps: wave-local, barrier-free ----
    float osum = 0.f;
    #pragma unroll
    for (int k = 0; k < 4; ++k) {
        const int L0 = 2 * k + ph;        // local rows L0, L0+1 (shared), L0+2
        f32x16 acc0, acc1;
        #pragma unroll
        for (int reg = 0; reg < 16; ++reg) { acc0[reg] = cb[reg]; acc1[reg] = cb[reg]; }
        __builtin_amdgcn_s_setprio(1);
        #pragma unroll
        for (int b = 0; b < 2; ++b) {
            int colp = ln + (pw - b) + 1;
            const short* p0 = &xs[L0][colp][half * 8];
            const short* p1 = &xs[L0 + 1][colp][half * 8];
            const short* p2 = &xs[L0 + 2][colp][half * 8];
            #pragma unroll
            for (int c = 0; c < 4; ++c) {
                short8 Fs = *(const short8*)(p1 + c * 16);   // shared middle row
                acc0 = __builtin_amdgcn_mfma_f32_32x32x16_bf16(af[4*b+c],   Fs, acc0, 0, 0, 0);
                acc1 = __builtin_amdgcn_mfma_f32_32x32x16_bf16(af[8+4*b+c], Fs, acc1, 0, 0, 0);
                short8 F0 = *(const short8*)(p0 + c * 16);
                acc0 = __builtin_amdgcn_mfma_f32_32x32x16_bf16(af[8+4*b+c], F0, acc0, 0, 0, 0);
                short8 F2 = *(const short8*)(p2 + c * 16);
                acc1 = __builtin_amdgcn_mfma_f32_32x32x16_bf16(af[4*b+c],   F2, acc1, 0, 0, 0);
            }
        }
        __builtin_amdgcn_s_setprio(0);

        // tree min-reduce over the 16 accumulator rows (co), both row-pairs
        float mn0, mn1;
        {
            float a = fminf(fminf(acc0[0], acc0[1]), fminf(acc0[2], acc0[3]));
            float b2 = fminf(fminf(acc0[4], acc0[5]), fminf(acc0[6], acc0[7]));
            float c = fminf(fminf(acc0[8], acc0[9]), fminf(acc0[10], acc0[11]));
            float d = fminf(fminf(acc0[12], acc0[13]), fminf(acc0[14], acc0[15]));
            mn0 = fminf(fminf(a, b2), fminf(c, d));
            a = fminf(fminf(acc1[0], acc1[1]), fminf(acc1[2], acc1[3]));
            b2 = fminf(fminf(acc1[4], acc1[5]), fminf(acc1[6], acc1[7]));
            c = fminf(fminf(acc1[8], acc1[9]), fminf(acc1[10], acc1[11]));
            d = fminf(fminf(acc1[12], acc1[13]), fminf(acc1[14], acc1[15]));
            mn1 = fminf(fminf(a, b2), fminf(c, d));
        }
        mn0 = fminf(mn0, __shfl_xor(mn0, 32, 64));   // fold co halves
        mn1 = fminf(mn1, __shfl_xor(mn1, 32, 64));
        osum += mn0 + mn1;                           // height-sum (linear)
    }

    if (half == 0) minbuf[wv][ln] = osum;
    bar_lds();

    // combine ph=0 + ph=1 for each pw -> one partial store per output column
    if (t < 64) {
        int c = t & 31, pwp = t >> 5;
        float v = minbuf[pwp][c] + minbuf[2 + pwp][c];
        int ow = ((jq * 32 + c) << 1) | pwp;
        partials[(size_t)st * 4096 + n * 256 + ow] = v;
    }
}

// Sum 16 strip-partials, GELU(tanh) + bias.
__global__ void finalize(const float* __restrict__ partials,
                         const float* __restrict__ bias, float* __restrict__ out)
{
    int idx = blockIdx.x * 256 + threadIdx.x;  // 0..4095
    float s = 0.f;
    #pragma unroll
    for (int st = 0; st < 16; ++st) s += partials[st * 4096 + idx];
    float u = 0.7978845608028654f * (s + 0.044715f * s * s * s);
    out[idx] = 0.5f * s * (1.f + tanhf(u)) + bias[0];
}

extern "C" void kernel_launch(void* const* d_in, const int* in_sizes, int n_in,
                              void* d_out, int out_size, void* d_ws, size_t ws_size,
                              hipStream_t stream) {
    const float* x      = (const float*)d_in[0];   // [16,64,128,128]
    const float* w      = (const float*)d_in[1];   // [64,32,4,4]
    const float* conv_b = (const float*)d_in[2];   // [32]
    const float* bias   = (const float*)d_in[3];   // [1]
    float* out = (float*)d_out;                    // 16*256

    short* wfrag    = (short*)d_ws;                      // 64 KB
    float* partials = (float*)((char*)d_ws + 65536);     // 16*4096 floats = 256 KB

    hipLaunchKernelGGL(prep, dim3(128), dim3(256), 0, stream, w, wfrag);
    hipLaunchKernelGGL(convt_mfma, dim3(16 * 16 * 4), dim3(256), 0, stream,
                       x, wfrag, conv_b, partials);
    hipLaunchKernelGGL(finalize, dim3(16), dim3(256), 0, stream,
                       partials, bias, out);
}